// Round 1
// baseline (455.648 us; speedup 1.0000x reference)
//
#include <hip/hip_runtime.h>

#define BS 64
#define S  512
#define E  1024
#define H  16
#define HD 64
#define SCALE 0.125f   // 1/sqrt(64)

// workspace float offsets
#define W_Q   1024
#define W_QK  66560
#define W_SC  1115136
#define W_P   1639424
#define W_CTX 2688000

__device__ __forceinline__ float wave_reduce_sum(float v) {
    #pragma unroll
    for (int off = 32; off > 0; off >>= 1) v += __shfl_xor(v, off, 64);
    return v;
}

// ---- 1. find first MASK position per batch ----
__global__ void k_maskpos(const int* __restrict__ ids, const int* __restrict__ mask_id_p,
                          int* __restrict__ mp_out) {
    int b = blockIdx.x;
    int mid = mask_id_p[0];
    int l = threadIdx.x;
    int best = S;
    for (int s = l; s < S; s += 64)
        if (ids[b * S + s] == mid && s < best) best = s;
    #pragma unroll
    for (int off = 32; off > 0; off >>= 1) {
        int o = __shfl_xor(best, off, 64);
        if (o < best) best = o;
    }
    if (l == 0) mp_out[b] = (best == S) ? 0 : best;  // argmax of all-false = 0
}

// ---- 2. q[b,j] = bq[j] + sum_e q_in[b,e] * Wq[j,e] ----
__global__ void k_q(const float* __restrict__ model, const float* __restrict__ knowledge,
                    const float* __restrict__ w_in, const float* __restrict__ b_in,
                    const int* __restrict__ ids, const int* __restrict__ know_id_p,
                    const int* __restrict__ mp, float* __restrict__ q) {
    int jt = blockIdx.x, b = blockIdx.y, tid = threadIdx.x;
    __shared__ float qin[E];
    int m = mp[b];
    bool isk = (ids[b * S + m] == know_id_p[0]);
    const float* src = isk ? (knowledge + (size_t)b * E) : (model + ((size_t)(b * S + m)) * E);
    for (int e = tid; e < E; e += 256) qin[e] = src[e];
    __syncthreads();
    int j = jt * 256 + tid;
    const float4* w4 = (const float4*)(w_in + (size_t)j * E);
    float acc = b_in[j];
    #pragma unroll 4
    for (int e = 0; e < E / 4; e++) {
        float4 w = w4[e];
        acc += qin[4*e] * w.x + qin[4*e+1] * w.y + qin[4*e+2] * w.z + qin[4*e+3] * w.w;
    }
    q[b * E + j] = acc;
}

// ---- 3. qk[b,h,e'] = sum_d q[b,h*64+d] * Wk[h*64+d, e']  (bk dropped: softmax shift-invariant) ----
__global__ void k_qk(const float* __restrict__ w_in, const float* __restrict__ q,
                     float* __restrict__ qk) {
    int et = blockIdx.x, h = blockIdx.y, b0 = blockIdx.z * 8, tid = threadIdx.x;
    __shared__ float qs[8][HD];
    for (int idx = tid; idx < 8 * HD; idx += 256) {
        int bl = idx / HD, d = idx % HD;
        qs[bl][d] = q[(b0 + bl) * E + h * HD + d];
    }
    __syncthreads();
    int ep = et * 256 + tid;
    const float* wk = w_in + (size_t)E * E;  // Wk = in_proj_weight[E:2E]
    float acc[8];
    #pragma unroll
    for (int i = 0; i < 8; i++) acc[i] = 0.f;
    for (int d = 0; d < HD; d++) {
        float w = wk[((size_t)(h * HD + d)) * E + ep];  // coalesced over threads
        #pragma unroll
        for (int i = 0; i < 8; i++) acc[i] += qs[i][d] * w;
    }
    #pragma unroll
    for (int i = 0; i < 8; i++)
        qk[((size_t)(b0 + i) * H + h) * E + ep] = acc[i];
}

// ---- 4. scores[b,h,s] = SCALE * sum_e qk[b,h,e] * kv[b,s,e] ----
__global__ void k_scores(const float* __restrict__ model, const float* __restrict__ knowledge,
                         const int* __restrict__ ids, const int* __restrict__ know_id_p,
                         const float* __restrict__ qk, float* __restrict__ sc) {
    int st = blockIdx.x, b = blockIdx.y, tid = threadIdx.x;
    int s0 = st * 64;
    __shared__ float kvt[64][65];
    __shared__ float qkt[16][64];
    __shared__ int knows[64];
    if (tid < 64) knows[tid] = (ids[b * S + s0 + tid] == know_id_p[0]) ? 1 : 0;
    __syncthreads();
    int hh = tid >> 5;   // 0..7 -> h pair
    int ss = tid & 31;   // 0..31 -> s pair
    float a00 = 0.f, a01 = 0.f, a10 = 0.f, a11 = 0.f;
    for (int e0 = 0; e0 < E; e0 += 64) {
        __syncthreads();
        for (int idx = tid; idx < 4096; idx += 256) {
            int sl = idx >> 6, el = idx & 63;
            kvt[sl][el] = knows[sl] ? knowledge[(size_t)b * E + e0 + el]
                                    : model[((size_t)(b * S + s0 + sl)) * E + e0 + el];
        }
        for (int idx = tid; idx < 1024; idx += 256) {
            int hl = idx >> 6, el = idx & 63;
            qkt[hl][el] = qk[((size_t)b * H + hl) * E + e0 + el];
        }
        __syncthreads();
        int h2 = hh * 2, s2 = ss * 2;
        #pragma unroll 8
        for (int i = 0; i < 64; i++) {
            float k0 = kvt[s2][i], k1 = kvt[s2 + 1][i];
            float q0 = qkt[h2][i], q1 = qkt[h2 + 1][i];
            a00 += q0 * k0; a01 += q0 * k1; a10 += q1 * k0; a11 += q1 * k1;
        }
    }
    int h2 = hh * 2, s2 = ss * 2;
    sc[((size_t)b * H + h2) * S + s0 + s2]         = a00 * SCALE;
    sc[((size_t)b * H + h2) * S + s0 + s2 + 1]     = a01 * SCALE;
    sc[((size_t)b * H + h2 + 1) * S + s0 + s2]     = a10 * SCALE;
    sc[((size_t)b * H + h2 + 1) * S + s0 + s2 + 1] = a11 * SCALE;
}

// ---- 5. softmax over s per (b,h), in place ----
__global__ void k_softmax(float* __restrict__ sc) {
    int h = blockIdx.x, b = blockIdx.y, l = threadIdx.x;
    float* row = sc + ((size_t)b * H + h) * S;
    float v[8];
    float m = -1e30f;
    #pragma unroll
    for (int i = 0; i < 8; i++) { v[i] = row[l + i * 64]; m = fmaxf(m, v[i]); }
    #pragma unroll
    for (int off = 32; off > 0; off >>= 1) m = fmaxf(m, __shfl_xor(m, off, 64));
    float sum = 0.f;
    #pragma unroll
    for (int i = 0; i < 8; i++) { v[i] = __expf(v[i] - m); sum += v[i]; }
    sum = wave_reduce_sum(sum);
    float inv = 1.0f / sum;
    #pragma unroll
    for (int i = 0; i < 8; i++) row[l + i * 64] = v[i] * inv;
}

// ---- 6. p[b,h,e] = sum_s attn[b,h,s] * kv[b,s,e] ----
__global__ void k_pacc(const float* __restrict__ model, const float* __restrict__ knowledge,
                       const int* __restrict__ ids, const int* __restrict__ know_id_p,
                       const float* __restrict__ attn, float* __restrict__ p) {
    int et = blockIdx.x, b = blockIdx.y, tid = threadIdx.x;
    int e0 = et * 64;
    __shared__ float kvt[64][65];
    __shared__ float att[16][64];
    __shared__ int knows[64];
    int kid = know_id_p[0];
    int hh = tid >> 5, ee = tid & 31;
    float a00 = 0.f, a01 = 0.f, a10 = 0.f, a11 = 0.f;
    for (int s0 = 0; s0 < S; s0 += 64) {
        __syncthreads();
        if (tid < 64) knows[tid] = (ids[b * S + s0 + tid] == kid) ? 1 : 0;
        __syncthreads();
        for (int idx = tid; idx < 4096; idx += 256) {
            int sl = idx >> 6, el = idx & 63;
            kvt[sl][el] = knows[sl] ? knowledge[(size_t)b * E + e0 + el]
                                    : model[((size_t)(b * S + s0 + sl)) * E + e0 + el];
        }
        for (int idx = tid; idx < 1024; idx += 256) {
            int hl = idx >> 6, sl = idx & 63;
            att[hl][sl] = attn[((size_t)b * H + hl) * S + s0 + sl];
        }
        __syncthreads();
        int h2 = hh * 2, e2 = ee * 2;
        #pragma unroll 8
        for (int j = 0; j < 64; j++) {
            float w0 = att[h2][j], w1 = att[h2 + 1][j];
            float k0 = kvt[j][e2], k1 = kvt[j][e2 + 1];
            a00 += w0 * k0; a01 += w0 * k1; a10 += w1 * k0; a11 += w1 * k1;
        }
    }
    int h2 = hh * 2, e2 = ee * 2;
    p[((size_t)b * H + h2) * E + e0 + e2]         = a00;
    p[((size_t)b * H + h2) * E + e0 + e2 + 1]     = a01;
    p[((size_t)b * H + h2 + 1) * E + e0 + e2]     = a10;
    p[((size_t)b * H + h2 + 1) * E + e0 + e2 + 1] = a11;
}

// ---- 7. ctx[b,r] = bv[r] + sum_e p[b, r/64, e] * Wv[r,e] ----
__global__ void k_ctx(const float* __restrict__ w_in, const float* __restrict__ b_in,
                      const float* __restrict__ p, float* __restrict__ ctx) {
    int rt = blockIdx.x, b = blockIdx.y, tid = threadIdx.x;
    __shared__ float pt[4][E];
    int h0 = rt * 4;
    for (int idx = tid; idx < 4 * E; idx += 256) {
        int hl = idx >> 10, el = idx & 1023;
        pt[hl][el] = p[((size_t)b * H + h0 + hl) * E + el];
    }
    __syncthreads();
    int r = rt * 256 + tid;
    const float* prow = pt[tid >> 6];   // h(r) - h0 = tid/64 (wave-uniform -> LDS broadcast)
    const float4* w4 = (const float4*)(w_in + (size_t)2 * E * E + (size_t)r * E);
    float acc = b_in[2 * E + r];
    #pragma unroll 4
    for (int e = 0; e < E / 4; e++) {
        float4 w = w4[e];
        acc += prow[4*e] * w.x + prow[4*e+1] * w.y + prow[4*e+2] * w.z + prow[4*e+3] * w.w;
    }
    ctx[b * E + r] = acc;
}

// ---- 8. out[b,j] = origin_q + strength * (ctx @ Wout^T + bout), gated by empty mask ----
__global__ void k_out(const float* __restrict__ model, const float* __restrict__ w_out,
                      const float* __restrict__ b_out, const float* __restrict__ ctx,
                      const int* __restrict__ mp, const int* __restrict__ empty,
                      const float* __restrict__ strength_p, float* __restrict__ out) {
    int jt = blockIdx.x, b = blockIdx.y, tid = threadIdx.x;
    __shared__ float ct[E];
    for (int e = tid; e < E; e += 256) ct[e] = ctx[b * E + e];
    __syncthreads();
    int j = jt * 256 + tid;
    int m = mp[b];
    float orig = model[((size_t)(b * S + m)) * E + j];
    float res;
    if (empty[b]) {
        res = orig;
    } else {
        float acc = b_out[j];
        const float4* w4 = (const float4*)(w_out + (size_t)j * E);
        #pragma unroll 4
        for (int r = 0; r < E / 4; r++) {
            float4 w = w4[r];
            acc += ct[4*r] * w.x + ct[4*r+1] * w.y + ct[4*r+2] * w.z + ct[4*r+3] * w.w;
        }
        res = orig + strength_p[0] * acc;
    }
    out[b * E + j] = res;
}

extern "C" void kernel_launch(void* const* d_in, const int* in_sizes, int n_in,
                              void* d_out, int out_size, void* d_ws, size_t ws_size,
                              hipStream_t stream) {
    const float* model     = (const float*)d_in[0];   // (64,512,1024) f32
    const float* knowledge = (const float*)d_in[1];   // (64,1024) f32
    const float* w_in      = (const float*)d_in[2];   // (3072,1024) f32
    const float* b_in      = (const float*)d_in[3];   // (3072,) f32
    const float* w_out     = (const float*)d_in[4];   // (1024,1024) f32
    const float* b_out     = (const float*)d_in[5];   // (1024,) f32
    const float* strength  = (const float*)d_in[6];   // scalar f32
    const int*   ids       = (const int*)d_in[7];     // (64,512) i32
    const int*   empty     = (const int*)d_in[8];     // (64,) bool->i32 (assumed)
    const int*   know_id   = (const int*)d_in[9];     // scalar i32
    const int*   mask_id   = (const int*)d_in[10];    // scalar i32
    float* out = (float*)d_out;

    float* ws  = (float*)d_ws;
    int*   mp  = (int*)d_ws;
    float* q   = ws + W_Q;
    float* qk  = ws + W_QK;
    float* sc  = ws + W_SC;
    float* p   = ws + W_P;
    float* ctx = ws + W_CTX;

    k_maskpos<<<BS, 64, 0, stream>>>(ids, mask_id, mp);
    k_q<<<dim3(4, BS), 256, 0, stream>>>(model, knowledge, w_in, b_in, ids, know_id, mp, q);
    k_qk<<<dim3(4, H, 8), 256, 0, stream>>>(w_in, q, qk);
    k_scores<<<dim3(8, BS), 256, 0, stream>>>(model, knowledge, ids, know_id, qk, sc);
    k_softmax<<<dim3(H, BS), 64, 0, stream>>>(sc);
    k_pacc<<<dim3(16, BS), 256, 0, stream>>>(model, knowledge, ids, know_id, sc, p);
    k_ctx<<<dim3(4, BS), 256, 0, stream>>>(w_in, b_in, p, ctx);
    k_out<<<dim3(4, BS), 256, 0, stream>>>(model, w_out, b_out, ctx, mp, empty, strength, out);
}

// Round 2
// 397.685 us; speedup vs baseline: 1.1458x; 1.1458x over previous
//
#include <hip/hip_runtime.h>

#define BS 64
#define S  512
#define E  1024
#define H  16
#define HD 64
#define SCALE 0.125f   // 1/sqrt(64)

// workspace float offsets
#define W_Q    1024
#define W_QK   66560
#define W_SC   1115136
#define W_PART 1639424
#define CHUNK_STRIDE 1048576   // BS*H*E floats per pacc partial

__device__ __forceinline__ void bfly4(float& a0, float& a1, float& a2, float& a3) {
    #pragma unroll
    for (int off = 32; off > 0; off >>= 1) {
        a0 += __shfl_xor(a0, off, 64);
        a1 += __shfl_xor(a1, off, 64);
        a2 += __shfl_xor(a2, off, 64);
        a3 += __shfl_xor(a3, off, 64);
    }
}

__device__ __forceinline__ void fma4(float4& acc, float s, const float4& v) {
    acc.x += s * v.x; acc.y += s * v.y; acc.z += s * v.z; acc.w += s * v.w;
}

__device__ __forceinline__ float dot4(const float4& a, const float4& b) {
    return a.x * b.x + a.y * b.y + a.z * b.z + a.w * b.w;
}

// ---- 1. first MASK position per batch ----
__global__ void k_maskpos(const int* __restrict__ ids, const int* __restrict__ mask_id_p,
                          int* __restrict__ mp_out) {
    int b = blockIdx.x;
    int mid = mask_id_p[0];
    int l = threadIdx.x;
    int best = S;
    for (int s = l; s < S; s += 64)
        if (ids[b * S + s] == mid && s < best) best = s;
    #pragma unroll
    for (int off = 32; off > 0; off >>= 1) {
        int o = __shfl_xor(best, off, 64);
        if (o < best) best = o;
    }
    if (l == 0) mp_out[b] = (best == S) ? 0 : best;
}

// ---- 2. q[b,j] = bq[j] + q_in[b]·Wq[j]  (wave per j, 4 b per wave) ----
__global__ void k_q(const float* __restrict__ model, const float* __restrict__ knowledge,
                    const float* __restrict__ w_in, const float* __restrict__ b_in,
                    const int* __restrict__ ids, const int* __restrict__ kid_p,
                    const int* __restrict__ mp, float* __restrict__ q) {
    int w = threadIdx.x >> 6, l = threadIdx.x & 63;
    int j = blockIdx.x * 4 + w;
    int b0 = blockIdx.y * 4;
    int kid = kid_p[0];
    const float* src[4];
    #pragma unroll
    for (int bb = 0; bb < 4; bb++) {
        int b = b0 + bb; int m = mp[b];
        src[bb] = (ids[b * S + m] == kid) ? knowledge + (size_t)b * E
                                          : model + ((size_t)(b * S + m)) * E;
    }
    const float* wr = w_in + (size_t)j * E;
    float a0 = 0.f, a1 = 0.f, a2 = 0.f, a3 = 0.f;
    #pragma unroll
    for (int r = 0; r < 4; r++) {
        int e = r * 256 + l * 4;
        float4 wv = *(const float4*)(wr + e);
        a0 += dot4(wv, *(const float4*)(src[0] + e));
        a1 += dot4(wv, *(const float4*)(src[1] + e));
        a2 += dot4(wv, *(const float4*)(src[2] + e));
        a3 += dot4(wv, *(const float4*)(src[3] + e));
    }
    bfly4(a0, a1, a2, a3);
    if (l == 0) {
        float bias = b_in[j];
        q[(size_t)(b0 + 0) * E + j] = a0 + bias;
        q[(size_t)(b0 + 1) * E + j] = a1 + bias;
        q[(size_t)(b0 + 2) * E + j] = a2 + bias;
        q[(size_t)(b0 + 3) * E + j] = a3 + bias;
    }
}

// ---- 3. qk[b,h,e'] = sum_d q[b,h*64+d] * Wk[h*64+d, e'] ----
__global__ void k_qk(const float* __restrict__ w_in, const float* __restrict__ q,
                     float* __restrict__ qk) {
    int et = blockIdx.x, h = blockIdx.y, b0 = blockIdx.z * 8, tid = threadIdx.x;
    __shared__ float qs[8][HD];
    for (int idx = tid; idx < 8 * HD; idx += 256) {
        int bl = idx / HD, d = idx % HD;
        qs[bl][d] = q[(b0 + bl) * E + h * HD + d];
    }
    __syncthreads();
    int ep = et * 256 + tid;
    const float* wk = w_in + (size_t)E * E;
    float acc[8];
    #pragma unroll
    for (int i = 0; i < 8; i++) acc[i] = 0.f;
    for (int d = 0; d < HD; d++) {
        float w = wk[((size_t)(h * HD + d)) * E + ep];
        #pragma unroll
        for (int i = 0; i < 8; i++) acc[i] += qs[i][d] * w;
    }
    #pragma unroll
    for (int i = 0; i < 8; i++)
        qk[((size_t)(b0 + i) * H + h) * E + ep] = acc[i];
}

// ---- 4. scores: wave per (row-group, 4h); lanes over e; butterfly reduce ----
__global__ void k_scores(const float* __restrict__ model, const float* __restrict__ knowledge,
                         const int* __restrict__ ids, const int* __restrict__ kid_p,
                         const float* __restrict__ qk, float* __restrict__ sc) {
    int w = threadIdx.x >> 6, l = threadIdx.x & 63;
    int b = blockIdx.y, s0 = blockIdx.x * 32;
    int kid = kid_p[0];
    float4 qreg[4][4];
    const float* qkb = qk + ((size_t)b * H + w * 4) * E;
    #pragma unroll
    for (int h = 0; h < 4; h++)
        #pragma unroll
        for (int r = 0; r < 4; r++)
            qreg[h][r] = *(const float4*)(qkb + (size_t)h * E + r * 256 + l * 4);
    const float* kb = knowledge + (size_t)b * E;
    for (int si = 0; si < 32; si += 2) {
        int sA = s0 + si, sB = s0 + si + 1;
        const float* rowA = (ids[b * S + sA] == kid) ? kb : model + ((size_t)(b * S + sA)) * E;
        const float* rowB = (ids[b * S + sB] == kid) ? kb : model + ((size_t)(b * S + sB)) * E;
        float4 A[4], Bv[4];
        #pragma unroll
        for (int r = 0; r < 4; r++) {
            A[r]  = *(const float4*)(rowA + r * 256 + l * 4);
            Bv[r] = *(const float4*)(rowB + r * 256 + l * 4);
        }
        float a0 = 0.f, a1 = 0.f, a2 = 0.f, a3 = 0.f;
        float c0 = 0.f, c1 = 0.f, c2 = 0.f, c3 = 0.f;
        #pragma unroll
        for (int r = 0; r < 4; r++) {
            a0 += dot4(qreg[0][r], A[r]);  c0 += dot4(qreg[0][r], Bv[r]);
            a1 += dot4(qreg[1][r], A[r]);  c1 += dot4(qreg[1][r], Bv[r]);
            a2 += dot4(qreg[2][r], A[r]);  c2 += dot4(qreg[2][r], Bv[r]);
            a3 += dot4(qreg[3][r], A[r]);  c3 += dot4(qreg[3][r], Bv[r]);
        }
        bfly4(a0, a1, a2, a3);
        bfly4(c0, c1, c2, c3);
        if (l == 0) {
            size_t base = ((size_t)b * H + w * 4) * S;
            sc[base + sA]         = a0 * SCALE;  sc[base + sB]         = c0 * SCALE;
            sc[base + S + sA]     = a1 * SCALE;  sc[base + S + sB]     = c1 * SCALE;
            sc[base + 2 * S + sA] = a2 * SCALE;  sc[base + 2 * S + sB] = c2 * SCALE;
            sc[base + 3 * S + sA] = a3 * SCALE;  sc[base + 3 * S + sB] = c3 * SCALE;
        }
    }
}

// ---- 5. softmax over s per (b,h), in place ----
__global__ void k_softmax(float* __restrict__ sc) {
    int h = blockIdx.x, b = blockIdx.y, l = threadIdx.x;
    float* row = sc + ((size_t)b * H + h) * S;
    float v[8];
    float m = -1e30f;
    #pragma unroll
    for (int i = 0; i < 8; i++) { v[i] = row[l + i * 64]; m = fmaxf(m, v[i]); }
    #pragma unroll
    for (int off = 32; off > 0; off >>= 1) m = fmaxf(m, __shfl_xor(m, off, 64));
    float sum = 0.f;
    #pragma unroll
    for (int i = 0; i < 8; i++) { v[i] = __expf(v[i] - m); sum += v[i]; }
    #pragma unroll
    for (int off = 32; off > 0; off >>= 1) sum += __shfl_xor(sum, off, 64);
    float inv = 1.0f / sum;
    #pragma unroll
    for (int i = 0; i < 8; i++) row[l + i * 64] = v[i] * inv;
}

// ---- 6. pacc partials: wave per 4h; lanes over e; accumulate over chunk rows ----
__global__ void k_pacc(const float* __restrict__ model, const float* __restrict__ knowledge,
                       const int* __restrict__ ids, const int* __restrict__ kid_p,
                       const float* __restrict__ attn, float* __restrict__ part,
                       int chunkS, int lgS) {
    __shared__ float wl[256 * 16];
    int w = threadIdx.x >> 6, l = threadIdx.x & 63, tid = threadIdx.x;
    int c = blockIdx.x, b = blockIdx.y;
    int s0 = c * chunkS;
    int kid = kid_p[0];
    int sMask = chunkS - 1;
    for (int idx = tid; idx < chunkS * 16; idx += 256) {
        int s = idx & sMask, h = idx >> lgS;
        wl[s * 16 + h] = attn[((size_t)b * H + h) * S + s0 + s];
    }
    __syncthreads();
    float4 p4[4][4];
    #pragma unroll
    for (int h = 0; h < 4; h++)
        #pragma unroll
        for (int r = 0; r < 4; r++) p4[h][r] = make_float4(0.f, 0.f, 0.f, 0.f);
    const float* kb = knowledge + (size_t)b * E;
    for (int si = 0; si < chunkS; si += 2) {
        int sA = s0 + si, sB = s0 + si + 1;
        const float* rowA = (ids[b * S + sA] == kid) ? kb : model + ((size_t)(b * S + sA)) * E;
        const float* rowB = (ids[b * S + sB] == kid) ? kb : model + ((size_t)(b * S + sB)) * E;
        float4 A[4], Bv[4];
        #pragma unroll
        for (int r = 0; r < 4; r++) {
            A[r]  = *(const float4*)(rowA + r * 256 + l * 4);
            Bv[r] = *(const float4*)(rowB + r * 256 + l * 4);
        }
        float4 wa = *(const float4*)&wl[si * 16 + w * 4];
        float4 wb = *(const float4*)&wl[(si + 1) * 16 + w * 4];
        #pragma unroll
        for (int r = 0; r < 4; r++) {
            fma4(p4[0][r], wa.x, A[r]);  fma4(p4[0][r], wb.x, Bv[r]);
            fma4(p4[1][r], wa.y, A[r]);  fma4(p4[1][r], wb.y, Bv[r]);
            fma4(p4[2][r], wa.z, A[r]);  fma4(p4[2][r], wb.z, Bv[r]);
            fma4(p4[3][r], wa.w, A[r]);  fma4(p4[3][r], wb.w, Bv[r]);
        }
    }
    #pragma unroll
    for (int h = 0; h < 4; h++)
        #pragma unroll
        for (int r = 0; r < 4; r++)
            *(float4*)&part[(((size_t)c * BS + b) * H + w * 4 + h) * E + r * 256 + l * 4] = p4[h][r];
}

// ---- 7. combine partials -> p dense ----
__global__ void k_combine(const float* __restrict__ part, float* __restrict__ p, int C) {
    int i = blockIdx.x * 256 + threadIdx.x;   // float4 index, 262144 total
    const float4* pf = (const float4*)part;
    float4 a = pf[i];
    for (int c = 1; c < C; c++) {
        float4 t = pf[(size_t)i + (size_t)c * (CHUNK_STRIDE / 4)];
        a.x += t.x; a.y += t.y; a.z += t.z; a.w += t.w;
    }
    ((float4*)p)[i] = a;
}

// ---- 8. ctx[b,r] = bv[r] + p[b, r/64]·Wv[r]  (wave per r, 4 b per wave) ----
__global__ void k_ctx(const float* __restrict__ w_in, const float* __restrict__ b_in,
                      const float* __restrict__ p, float* __restrict__ ctx) {
    int w = threadIdx.x >> 6, l = threadIdx.x & 63;
    int j = blockIdx.x * 4 + w;
    int b0 = blockIdx.y * 4;
    int h = j >> 6;
    const float* wr = w_in + (size_t)2 * E * E + (size_t)j * E;
    float a0 = 0.f, a1 = 0.f, a2 = 0.f, a3 = 0.f;
    #pragma unroll
    for (int r = 0; r < 4; r++) {
        int e = r * 256 + l * 4;
        float4 wv = *(const float4*)(wr + e);
        a0 += dot4(wv, *(const float4*)(p + ((size_t)(b0 + 0) * H + h) * E + e));
        a1 += dot4(wv, *(const float4*)(p + ((size_t)(b0 + 1) * H + h) * E + e));
        a2 += dot4(wv, *(const float4*)(p + ((size_t)(b0 + 2) * H + h) * E + e));
        a3 += dot4(wv, *(const float4*)(p + ((size_t)(b0 + 3) * H + h) * E + e));
    }
    bfly4(a0, a1, a2, a3);
    if (l == 0) {
        float bias = b_in[2 * E + j];
        ctx[(size_t)(b0 + 0) * E + j] = a0 + bias;
        ctx[(size_t)(b0 + 1) * E + j] = a1 + bias;
        ctx[(size_t)(b0 + 2) * E + j] = a2 + bias;
        ctx[(size_t)(b0 + 3) * E + j] = a3 + bias;
    }
}

// ---- 9. out = origin_q + strength * (ctx·Wout^T + bout), gated ----
__global__ void k_out(const float* __restrict__ model, const float* __restrict__ w_out,
                      const float* __restrict__ b_out, const float* __restrict__ ctx,
                      const int* __restrict__ mp, const int* __restrict__ empty,
                      const float* __restrict__ strength_p, float* __restrict__ out) {
    int w = threadIdx.x >> 6, l = threadIdx.x & 63;
    int j = blockIdx.x * 4 + w;
    int b0 = blockIdx.y * 4;
    const float* wr = w_out + (size_t)j * E;
    float a0 = 0.f, a1 = 0.f, a2 = 0.f, a3 = 0.f;
    #pragma unroll
    for (int r = 0; r < 4; r++) {
        int e = r * 256 + l * 4;
        float4 wv = *(const float4*)(wr + e);
        a0 += dot4(wv, *(const float4*)(ctx + (size_t)(b0 + 0) * E + e));
        a1 += dot4(wv, *(const float4*)(ctx + (size_t)(b0 + 1) * E + e));
        a2 += dot4(wv, *(const float4*)(ctx + (size_t)(b0 + 2) * E + e));
        a3 += dot4(wv, *(const float4*)(ctx + (size_t)(b0 + 3) * E + e));
    }
    bfly4(a0, a1, a2, a3);
    if (l == 0) {
        float bias = b_out[j];
        float st = strength_p[0];
        float accs[4] = {a0, a1, a2, a3};
        #pragma unroll
        for (int bb = 0; bb < 4; bb++) {
            int b = b0 + bb;
            int m = mp[b];
            float orig = model[((size_t)(b * S + m)) * E + j];
            out[(size_t)b * E + j] = empty[b] ? orig : orig + st * (accs[bb] + bias);
        }
    }
}

extern "C" void kernel_launch(void* const* d_in, const int* in_sizes, int n_in,
                              void* d_out, int out_size, void* d_ws, size_t ws_size,
                              hipStream_t stream) {
    const float* model     = (const float*)d_in[0];
    const float* knowledge = (const float*)d_in[1];
    const float* w_in      = (const float*)d_in[2];
    const float* b_in      = (const float*)d_in[3];
    const float* w_out     = (const float*)d_in[4];
    const float* b_out     = (const float*)d_in[5];
    const float* strength  = (const float*)d_in[6];
    const int*   ids       = (const int*)d_in[7];
    const int*   empty     = (const int*)d_in[8];
    const int*   know_id   = (const int*)d_in[9];
    const int*   mask_id   = (const int*)d_in[10];
    float* out = (float*)d_out;

    float* ws  = (float*)d_ws;
    int*   mp  = (int*)d_ws;
    float* q   = ws + W_Q;
    float* qk  = ws + W_QK;
    float* sc  = ws + W_SC;
    float* part = ws + W_PART;

    // pick pacc chunk count from workspace budget (constant per deployment -> graph-safe)
    int C = 8, lgS = 6;
    size_t need = ((size_t)W_PART + 8 * CHUNK_STRIDE + CHUNK_STRIDE + 65536) * 4;
    if (ws_size < need) { C = 4; lgS = 7; need = ((size_t)W_PART + 4 * CHUNK_STRIDE + CHUNK_STRIDE + 65536) * 4; }
    if (ws_size < need) { C = 2; lgS = 8; }
    int chunkS = S / C;

    float* p   = part + (size_t)C * CHUNK_STRIDE;
    float* ctx = p + CHUNK_STRIDE;

    k_maskpos<<<BS, 64, 0, stream>>>(ids, mask_id, mp);
    k_q<<<dim3(256, 16), 256, 0, stream>>>(model, knowledge, w_in, b_in, ids, know_id, mp, q);
    k_qk<<<dim3(4, H, 8), 256, 0, stream>>>(w_in, q, qk);
    k_scores<<<dim3(16, BS), 256, 0, stream>>>(model, knowledge, ids, know_id, qk, sc);
    k_softmax<<<dim3(H, BS), 64, 0, stream>>>(sc);
    k_pacc<<<dim3(C, BS), 256, 0, stream>>>(model, knowledge, ids, know_id, sc, part, chunkS, lgS);
    k_combine<<<dim3(1024), 256, 0, stream>>>(part, p, C);
    k_ctx<<<dim3(256, 16), 256, 0, stream>>>(w_in, b_in, p, ctx);
    k_out<<<dim3(256, 16), 256, 0, stream>>>(model, w_out, b_out, ctx, mp, empty, strength, out);
}

// Round 3
// 372.963 us; speedup vs baseline: 1.2217x; 1.0663x over previous
//
#include <hip/hip_runtime.h>

#define BS 64
#define S  512
#define E  1024
#define H  16
#define HD 64
#define SCALE 0.125f   // 1/sqrt(64)

// workspace float offsets
#define W_Q    1024
#define W_QK   66560        // 1024 + 64*1024
#define W_NUM  1115136      // W_QK + 64*16*1024

__device__ __forceinline__ void bfly4(float& a0, float& a1, float& a2, float& a3) {
    #pragma unroll
    for (int off = 32; off > 0; off >>= 1) {
        a0 += __shfl_xor(a0, off, 64);
        a1 += __shfl_xor(a1, off, 64);
        a2 += __shfl_xor(a2, off, 64);
        a3 += __shfl_xor(a3, off, 64);
    }
}

__device__ __forceinline__ void bfly8(float* a) {
    #pragma unroll
    for (int off = 32; off > 0; off >>= 1) {
        #pragma unroll
        for (int i = 0; i < 8; i++) a[i] += __shfl_xor(a[i], off, 64);
    }
}

__device__ __forceinline__ void fma4(float4& acc, float s, const float4& v) {
    acc.x += s * v.x; acc.y += s * v.y; acc.z += s * v.z; acc.w += s * v.w;
}

__device__ __forceinline__ float dot4(const float4& a, const float4& b) {
    return a.x * b.x + a.y * b.y + a.z * b.z + a.w * b.w;
}

// ---- 1. first MASK position per batch ----
__global__ void k_maskpos(const int* __restrict__ ids, const int* __restrict__ mask_id_p,
                          int* __restrict__ mp_out) {
    int b = blockIdx.x;
    int mid = mask_id_p[0];
    int l = threadIdx.x;
    int best = S;
    for (int s = l; s < S; s += 64)
        if (ids[b * S + s] == mid && s < best) best = s;
    #pragma unroll
    for (int off = 32; off > 0; off >>= 1) {
        int o = __shfl_xor(best, off, 64);
        if (o < best) best = o;
    }
    if (l == 0) mp_out[b] = (best == S) ? 0 : best;
}

// ---- 2. q[b,j] = bq[j] + q_in[b]·Wq[j]  (wave per j, 4 b per wave) ----
__global__ void k_q(const float* __restrict__ model, const float* __restrict__ knowledge,
                    const float* __restrict__ w_in, const float* __restrict__ b_in,
                    const int* __restrict__ ids, const int* __restrict__ kid_p,
                    const int* __restrict__ mp, float* __restrict__ q) {
    int w = threadIdx.x >> 6, l = threadIdx.x & 63;
    int j = blockIdx.x * 4 + w;
    int b0 = blockIdx.y * 4;
    int kid = kid_p[0];
    const float* src[4];
    #pragma unroll
    for (int bb = 0; bb < 4; bb++) {
        int b = b0 + bb; int m = mp[b];
        src[bb] = (ids[b * S + m] == kid) ? knowledge + (size_t)b * E
                                          : model + ((size_t)(b * S + m)) * E;
    }
    const float* wr = w_in + (size_t)j * E;
    float a0 = 0.f, a1 = 0.f, a2 = 0.f, a3 = 0.f;
    #pragma unroll
    for (int r = 0; r < 4; r++) {
        int e = r * 256 + l * 4;
        float4 wv = *(const float4*)(wr + e);
        a0 += dot4(wv, *(const float4*)(src[0] + e));
        a1 += dot4(wv, *(const float4*)(src[1] + e));
        a2 += dot4(wv, *(const float4*)(src[2] + e));
        a3 += dot4(wv, *(const float4*)(src[3] + e));
    }
    bfly4(a0, a1, a2, a3);
    if (l == 0) {
        float bias = b_in[j];
        q[(size_t)(b0 + 0) * E + j] = a0 + bias;
        q[(size_t)(b0 + 1) * E + j] = a1 + bias;
        q[(size_t)(b0 + 2) * E + j] = a2 + bias;
        q[(size_t)(b0 + 3) * E + j] = a3 + bias;
    }
}

// ---- 3. qk[b,h,e'] = sum_d q[b,h*64+d] * Wk[h*64+d, e'] (bk dropped: softmax shift-inv) ----
__global__ void k_qk(const float* __restrict__ w_in, const float* __restrict__ q,
                     float* __restrict__ qk) {
    int et = blockIdx.x, h = blockIdx.y, b0 = blockIdx.z * 8, tid = threadIdx.x;
    __shared__ float qs[8][HD];
    for (int idx = tid; idx < 8 * HD; idx += 256) {
        int bl = idx / HD, d = idx % HD;
        qs[bl][d] = q[(b0 + bl) * E + h * HD + d];
    }
    __syncthreads();
    int ep = et * 256 + tid;
    const float* wk = w_in + (size_t)E * E;
    float acc[8];
    #pragma unroll
    for (int i = 0; i < 8; i++) acc[i] = 0.f;
    for (int d = 0; d < HD; d++) {
        float w = wk[((size_t)(h * HD + d)) * E + ep];
        #pragma unroll
        for (int i = 0; i < 8; i++) acc[i] += qs[i][d] * w;
    }
    #pragma unroll
    for (int i = 0; i < 8; i++)
        qk[((size_t)(b0 + i) * H + h) * E + ep] = acc[i];
}

// ---- 4. fused scores+softmax+pacc (no-max online exp accumulation) ----
// grid (C, BS), block 512 (8 waves). Wave w handles heads {2w, 2w+1}.
// num[c,b,h,e] = sum_{s in chunk} exp(score)*kv[s,e];  den[c,b,h] = sum exp(score)
__global__ __launch_bounds__(512, 2) void k_attn(
    const float* __restrict__ model, const float* __restrict__ knowledge,
    const int* __restrict__ ids, const int* __restrict__ kid_p,
    const float* __restrict__ qk, float* __restrict__ num, float* __restrict__ den,
    int chunkS) {
    int tid = threadIdx.x;
    int w = tid >> 6, l = tid & 63;
    int c = blockIdx.x, b = blockIdx.y;
    int s0 = c * chunkS;
    int kid = kid_p[0];
    int h0 = w * 2;
    const float* qkb = qk + ((size_t)b * H + h0) * E;
    float4 q0[4], q1[4];
    #pragma unroll
    for (int r = 0; r < 4; r++) {
        q0[r] = *(const float4*)(qkb + r * 256 + l * 4);
        q1[r] = *(const float4*)(qkb + E + r * 256 + l * 4);
    }
    float4 n0[4], n1[4];
    #pragma unroll
    for (int r = 0; r < 4; r++) {
        n0[r] = make_float4(0.f, 0.f, 0.f, 0.f);
        n1[r] = make_float4(0.f, 0.f, 0.f, 0.f);
    }
    float d0 = 0.f, d1 = 0.f;
    const float* kb = knowledge + (size_t)b * E;
    const int* idsb = ids + b * S;
    const float* mb = model + (size_t)b * S * E;
    for (int si = 0; si < chunkS; si += 4) {
        const float* rp[4];
        #pragma unroll
        for (int t = 0; t < 4; t++) {
            int s = s0 + si + t;
            rp[t] = (idsb[s] == kid) ? kb : mb + (size_t)s * E;
        }
        float4 R[4][4];
        #pragma unroll
        for (int t = 0; t < 4; t++)
            #pragma unroll
            for (int r = 0; r < 4; r++)
                R[t][r] = *(const float4*)(rp[t] + r * 256 + l * 4);
        float sc[8];
        #pragma unroll
        for (int t = 0; t < 4; t++) {
            float a0 = 0.f, a1 = 0.f;
            #pragma unroll
            for (int r = 0; r < 4; r++) { a0 += dot4(q0[r], R[t][r]); a1 += dot4(q1[r], R[t][r]); }
            sc[t] = a0; sc[4 + t] = a1;
        }
        bfly8(sc);   // all lanes now hold the 8 full dot products
        float e0[4], e1[4];
        #pragma unroll
        for (int t = 0; t < 4; t++) {
            e0[t] = __expf(sc[t] * SCALE);
            e1[t] = __expf(sc[4 + t] * SCALE);
            d0 += e0[t]; d1 += e1[t];
        }
        #pragma unroll
        for (int t = 0; t < 4; t++)
            #pragma unroll
            for (int r = 0; r < 4; r++) { fma4(n0[r], e0[t], R[t][r]); fma4(n1[r], e1[t], R[t][r]); }
    }
    size_t obase = (((size_t)c * BS + b) * H + h0) * E;
    #pragma unroll
    for (int r = 0; r < 4; r++) {
        *(float4*)(num + obase + r * 256 + l * 4) = n0[r];
        *(float4*)(num + obase + E + r * 256 + l * 4) = n1[r];
    }
    if (l == 0) {
        den[((size_t)c * BS + b) * H + h0]     = d0;
        den[((size_t)c * BS + b) * H + h0 + 1] = d1;
    }
}

// ---- 5. combine partials: p[b,h,e] = sum_c num / sum_c den ----
__global__ void k_combine(const float* __restrict__ num, const float* __restrict__ den,
                          float* __restrict__ p, int C) {
    int i = blockIdx.x * 256 + threadIdx.x;   // float4 idx over BS*H*E/4 = 262144
    int bh = i >> 8;                          // E/4 = 256 float4 per (b,h)
    float4 a = make_float4(0.f, 0.f, 0.f, 0.f);
    float ds = 0.f;
    for (int c = 0; c < C; c++) {
        float4 t = ((const float4*)num)[(size_t)c * (BS * H * E / 4) + i];
        a.x += t.x; a.y += t.y; a.z += t.z; a.w += t.w;
        ds += den[(size_t)c * (BS * H) + bh];
    }
    float inv = 1.0f / ds;
    a.x *= inv; a.y *= inv; a.z *= inv; a.w *= inv;
    ((float4*)p)[i] = a;
}

// ---- 6. ctx[b,r] = bv[r] + p[b, r/64]·Wv[r]  (wave per r, 4 b per wave) ----
__global__ void k_ctx(const float* __restrict__ w_in, const float* __restrict__ b_in,
                      const float* __restrict__ p, float* __restrict__ ctx) {
    int w = threadIdx.x >> 6, l = threadIdx.x & 63;
    int j = blockIdx.x * 4 + w;
    int b0 = blockIdx.y * 4;
    int h = j >> 6;
    const float* wr = w_in + (size_t)2 * E * E + (size_t)j * E;
    float a0 = 0.f, a1 = 0.f, a2 = 0.f, a3 = 0.f;
    #pragma unroll
    for (int r = 0; r < 4; r++) {
        int e = r * 256 + l * 4;
        float4 wv = *(const float4*)(wr + e);
        a0 += dot4(wv, *(const float4*)(p + ((size_t)(b0 + 0) * H + h) * E + e));
        a1 += dot4(wv, *(const float4*)(p + ((size_t)(b0 + 1) * H + h) * E + e));
        a2 += dot4(wv, *(const float4*)(p + ((size_t)(b0 + 2) * H + h) * E + e));
        a3 += dot4(wv, *(const float4*)(p + ((size_t)(b0 + 3) * H + h) * E + e));
    }
    bfly4(a0, a1, a2, a3);
    if (l == 0) {
        float bias = b_in[2 * E + j];
        ctx[(size_t)(b0 + 0) * E + j] = a0 + bias;
        ctx[(size_t)(b0 + 1) * E + j] = a1 + bias;
        ctx[(size_t)(b0 + 2) * E + j] = a2 + bias;
        ctx[(size_t)(b0 + 3) * E + j] = a3 + bias;
    }
}

// ---- 7. out = origin_q + strength * (ctx·Wout^T + bout), gated ----
__global__ void k_out(const float* __restrict__ model, const float* __restrict__ w_out,
                      const float* __restrict__ b_out, const float* __restrict__ ctx,
                      const int* __restrict__ mp, const int* __restrict__ empty,
                      const float* __restrict__ strength_p, float* __restrict__ out) {
    int w = threadIdx.x >> 6, l = threadIdx.x & 63;
    int j = blockIdx.x * 4 + w;
    int b0 = blockIdx.y * 4;
    const float* wr = w_out + (size_t)j * E;
    float a0 = 0.f, a1 = 0.f, a2 = 0.f, a3 = 0.f;
    #pragma unroll
    for (int r = 0; r < 4; r++) {
        int e = r * 256 + l * 4;
        float4 wv = *(const float4*)(wr + e);
        a0 += dot4(wv, *(const float4*)(ctx + (size_t)(b0 + 0) * E + e));
        a1 += dot4(wv, *(const float4*)(ctx + (size_t)(b0 + 1) * E + e));
        a2 += dot4(wv, *(const float4*)(ctx + (size_t)(b0 + 2) * E + e));
        a3 += dot4(wv, *(const float4*)(ctx + (size_t)(b0 + 3) * E + e));
    }
    bfly4(a0, a1, a2, a3);
    if (l == 0) {
        float bias = b_out[j];
        float st = strength_p[0];
        float accs[4] = {a0, a1, a2, a3};
        #pragma unroll
        for (int bb = 0; bb < 4; bb++) {
            int b = b0 + bb;
            int m = mp[b];
            float orig = model[((size_t)(b * S + m)) * E + j];
            out[(size_t)b * E + j] = empty[b] ? orig : orig + st * (accs[bb] + bias);
        }
    }
}

extern "C" void kernel_launch(void* const* d_in, const int* in_sizes, int n_in,
                              void* d_out, int out_size, void* d_ws, size_t ws_size,
                              hipStream_t stream) {
    const float* model     = (const float*)d_in[0];
    const float* knowledge = (const float*)d_in[1];
    const float* w_in      = (const float*)d_in[2];
    const float* b_in      = (const float*)d_in[3];
    const float* w_out     = (const float*)d_in[4];
    const float* b_out     = (const float*)d_in[5];
    const float* strength  = (const float*)d_in[6];
    const int*   ids       = (const int*)d_in[7];
    const int*   empty     = (const int*)d_in[8];
    const int*   know_id   = (const int*)d_in[9];
    const int*   mask_id   = (const int*)d_in[10];
    float* out = (float*)d_out;

    float* ws  = (float*)d_ws;
    int*   mp  = (int*)d_ws;
    float* q   = ws + W_Q;
    float* qk  = ws + W_QK;
    float* num = ws + W_NUM;

    // choose partial-chunk count C from workspace budget (fixed per deployment -> graph-safe)
    int C = 8;
    {
        size_t need8 = ((size_t)W_NUM + 8u * 1048576u + 8u * 1024u + 1048576u + 65536u) * 4u;
        size_t need4 = ((size_t)W_NUM + 4u * 1048576u + 4u * 1024u + 1048576u + 65536u) * 4u;
        if (ws_size < need8) C = (ws_size < need4) ? 2 : 4;
    }
    int chunkS = S / C;
    float* den = num + (size_t)C * 1048576u;
    float* p   = den + (size_t)C * 1024u;
    float* ctx = p + 1048576u;

    k_maskpos<<<BS, 64, 0, stream>>>(ids, mask_id, mp);
    k_q<<<dim3(256, 16), 256, 0, stream>>>(model, knowledge, w_in, b_in, ids, know_id, mp, q);
    k_qk<<<dim3(4, H, 8), 256, 0, stream>>>(w_in, q, qk);
    k_attn<<<dim3(C, BS), 512, 0, stream>>>(model, knowledge, ids, know_id, qk, num, den, chunkS);
    k_combine<<<dim3(1024), 256, 0, stream>>>(num, den, p, C);
    k_ctx<<<dim3(256, 16), 256, 0, stream>>>(w_in, b_in, p, ctx);
    k_out<<<dim3(256, 16), 256, 0, stream>>>(model, w_out, b_out, ctx, mp, empty, strength, out);
}

// Round 4
// 368.051 us; speedup vs baseline: 1.2380x; 1.0133x over previous
//
#include <hip/hip_runtime.h>

#define BS 64
#define S  512
#define E  1024
#define H  16
#define HD 64
#define SCALE 0.125f   // 1/sqrt(64)

// workspace float offsets (total 10626048 floats = 42.50 MB, same as R3's known-good C=8 layout)
#define W_Q    1024
#define W_QK   66560        // 1024 + 64*1024
#define W_NUM  1115136      // W_QK + 64*16*1024

__device__ __forceinline__ void bfly4(float& a0, float& a1, float& a2, float& a3) {
    #pragma unroll
    for (int off = 32; off > 0; off >>= 1) {
        a0 += __shfl_xor(a0, off, 64);
        a1 += __shfl_xor(a1, off, 64);
        a2 += __shfl_xor(a2, off, 64);
        a3 += __shfl_xor(a3, off, 64);
    }
}

__device__ __forceinline__ void bfly8(float* a) {
    #pragma unroll
    for (int off = 32; off > 0; off >>= 1) {
        #pragma unroll
        for (int i = 0; i < 8; i++) a[i] += __shfl_xor(a[i], off, 64);
    }
}

__device__ __forceinline__ void fma4(float4& acc, float s, const float4& v) {
    acc.x += s * v.x; acc.y += s * v.y; acc.z += s * v.z; acc.w += s * v.w;
}

__device__ __forceinline__ float dot4(const float4& a, const float4& b) {
    return a.x * b.x + a.y * b.y + a.z * b.z + a.w * b.w;
}

// ---- 1. prep: mask position + gathered q-input row (qin lives in num area, written before k_attn) ----
__global__ void k_prep(const float* __restrict__ model, const float* __restrict__ knowledge,
                       const int* __restrict__ ids, const int* __restrict__ mask_id_p,
                       const int* __restrict__ kid_p, int* __restrict__ mp,
                       float* __restrict__ qin) {
    int b = blockIdx.x, tid = threadIdx.x;
    __shared__ int best;
    if (tid == 0) best = S;
    __syncthreads();
    int mid = mask_id_p[0];
    for (int s = tid; s < S; s += 256)
        if (ids[b * S + s] == mid) atomicMin(&best, s);
    __syncthreads();
    int m = (best == S) ? 0 : best;
    if (tid == 0) mp[b] = m;
    bool isk = (ids[b * S + m] == kid_p[0]);
    const float* qrow = isk ? knowledge + (size_t)b * E : model + ((size_t)(b * S + m)) * E;
    ((float4*)(qin + (size_t)b * E))[tid] = ((const float4*)qrow)[tid];
}

// ---- 2. q[b,j] = bq[j] + qin[b]·Wq[j]  (wave per j, 8 b per wave) ----
__global__ void k_q(const float* __restrict__ qin, const float* __restrict__ w_in,
                    const float* __restrict__ b_in, float* __restrict__ q) {
    int w = threadIdx.x >> 6, l = threadIdx.x & 63;
    int j = blockIdx.x * 4 + w;
    int b0 = blockIdx.y * 8;
    const float* wr = w_in + (size_t)j * E;
    float4 wv[4];
    #pragma unroll
    for (int r = 0; r < 4; r++) wv[r] = *(const float4*)(wr + r * 256 + l * 4);
    float acc[8];
    #pragma unroll
    for (int bb = 0; bb < 8; bb++) {
        const float* src = qin + (size_t)(b0 + bb) * E;
        float a = 0.f;
        #pragma unroll
        for (int r = 0; r < 4; r++) a += dot4(wv[r], *(const float4*)(src + r * 256 + l * 4));
        acc[bb] = a;
    }
    bfly8(acc);
    if (l == 0) {
        float bias = b_in[j];
        #pragma unroll
        for (int bb = 0; bb < 8; bb++) q[(size_t)(b0 + bb) * E + j] = acc[bb] + bias;
    }
}

// ---- 3. qk[b,h,e'] = sum_d q[b,h*64+d] * Wk[h*64+d, e'] (bk dropped: softmax shift-inv) ----
__global__ void k_qk(const float* __restrict__ w_in, const float* __restrict__ q,
                     float* __restrict__ qk) {
    int et = blockIdx.x, h = blockIdx.y, b0 = blockIdx.z * 8, tid = threadIdx.x;
    __shared__ float qs[8][HD];
    for (int idx = tid; idx < 8 * HD; idx += 256) {
        int bl = idx / HD, d = idx % HD;
        qs[bl][d] = q[(b0 + bl) * E + h * HD + d];
    }
    __syncthreads();
    int ep = et * 256 + tid;
    const float* wk = w_in + (size_t)E * E;
    float acc[8];
    #pragma unroll
    for (int i = 0; i < 8; i++) acc[i] = 0.f;
    for (int d = 0; d < HD; d++) {
        float w = wk[((size_t)(h * HD + d)) * E + ep];
        #pragma unroll
        for (int i = 0; i < 8; i++) acc[i] += qs[i][d] * w;
    }
    #pragma unroll
    for (int i = 0; i < 8; i++)
        qk[((size_t)(b0 + i) * H + h) * E + ep] = acc[i];
}

// ---- 4. fused scores+softmax+pacc, ids in registers, double-buffered row prefetch ----
// grid (8/nHalf, BS), block 512. Wave w handles heads {2w, 2w+1}; block covers nHalf*64 rows.
__global__ __launch_bounds__(512, 2) void k_attn(
    const float* __restrict__ model, const float* __restrict__ knowledge,
    const int* __restrict__ ids, const int* __restrict__ kid_p,
    const float* __restrict__ qk, float* __restrict__ num, float* __restrict__ den,
    int nHalf) {
    int tid = threadIdx.x;
    int w = tid >> 6, l = tid & 63;
    int c = blockIdx.x, b = blockIdx.y;
    int kid = kid_p[0];
    int h0 = w * 2;
    const float* qkb = qk + ((size_t)b * H + h0) * E;
    float4 q0[4], q1[4];
    #pragma unroll
    for (int r = 0; r < 4; r++) {
        q0[r] = *(const float4*)(qkb + r * 256 + l * 4);
        q1[r] = *(const float4*)(qkb + E + r * 256 + l * 4);
    }
    float4 n0[4], n1[4];
    #pragma unroll
    for (int r = 0; r < 4; r++) {
        n0[r] = make_float4(0.f, 0.f, 0.f, 0.f);
        n1[r] = make_float4(0.f, 0.f, 0.f, 0.f);
    }
    float d0 = 0.f, d1 = 0.f;
    const float* kb = knowledge + (size_t)b * E;
    const float* mb = model + (size_t)b * S * E;

    for (int half = 0; half < nHalf; half++) {
        int s0 = (c * nHalf + half) * 64;
        int myid = ids[b * S + s0 + l];   // lane l holds id of row s0+l

        float4 Ra[2][4], Rb[2][4];
        auto ldrows = [&](float4 Rt[2][4], int si) {
            #pragma unroll
            for (int t = 0; t < 2; t++) {
                int sm = (si + t) & 63;
                int idt = __shfl(myid, sm);
                const float* rp = (idt == kid) ? kb : mb + (size_t)(s0 + sm) * E;
                #pragma unroll
                for (int r = 0; r < 4; r++) Rt[t][r] = *(const float4*)(rp + r * 256 + l * 4);
            }
        };
        auto comp = [&](float4 Rt[2][4]) {
            float a00 = 0.f, a10 = 0.f, a01 = 0.f, a11 = 0.f;
            #pragma unroll
            for (int r = 0; r < 4; r++) {
                a00 += dot4(q0[r], Rt[0][r]); a10 += dot4(q0[r], Rt[1][r]);
                a01 += dot4(q1[r], Rt[0][r]); a11 += dot4(q1[r], Rt[1][r]);
            }
            bfly4(a00, a10, a01, a11);
            float e00 = __expf(a00 * SCALE), e10 = __expf(a10 * SCALE);
            float e01 = __expf(a01 * SCALE), e11 = __expf(a11 * SCALE);
            d0 += e00 + e10; d1 += e01 + e11;
            #pragma unroll
            for (int r = 0; r < 4; r++) {
                fma4(n0[r], e00, Rt[0][r]); fma4(n0[r], e10, Rt[1][r]);
                fma4(n1[r], e01, Rt[0][r]); fma4(n1[r], e11, Rt[1][r]);
            }
        };

        ldrows(Ra, 0);
        for (int si = 0; si < 64; si += 4) {
            ldrows(Rb, si + 2);
            comp(Ra);
            ldrows(Ra, (si + 4) & 63);   // wraps at end: harmless redundant load
            comp(Rb);
        }
    }

    size_t obase = (((size_t)c * BS + b) * H + h0) * E;
    #pragma unroll
    for (int r = 0; r < 4; r++) {
        *(float4*)(num + obase + r * 256 + l * 4) = n0[r];
        *(float4*)(num + obase + E + r * 256 + l * 4) = n1[r];
    }
    if (l == 0) {
        den[((size_t)c * BS + b) * H + h0]     = d0;
        den[((size_t)c * BS + b) * H + h0 + 1] = d1;
    }
}

// ---- 5. combine partials: p[b,h,e] = sum_c num / sum_c den ----
__global__ void k_combine(const float* __restrict__ num, const float* __restrict__ den,
                          float* __restrict__ p, int C) {
    int i = blockIdx.x * 256 + threadIdx.x;   // float4 idx over BS*H*E/4 = 262144
    int bh = i >> 8;                          // E/4 = 256 float4 per (b,h)
    float4 a = make_float4(0.f, 0.f, 0.f, 0.f);
    float ds = 0.f;
    for (int c = 0; c < C; c++) {
        float4 t = ((const float4*)num)[(size_t)c * (BS * H * E / 4) + i];
        a.x += t.x; a.y += t.y; a.z += t.z; a.w += t.w;
        ds += den[(size_t)c * (BS * H) + bh];
    }
    float inv = 1.0f / ds;
    a.x *= inv; a.y *= inv; a.z *= inv; a.w *= inv;
    ((float4*)p)[i] = a;
}

// ---- 6. ctx[b,j] = bv[j] + p[b, j/64]·Wv[j]  (wave per j, 8 b per wave) ----
__global__ void k_ctx(const float* __restrict__ w_in, const float* __restrict__ b_in,
                      const float* __restrict__ p, float* __restrict__ ctx) {
    int w = threadIdx.x >> 6, l = threadIdx.x & 63;
    int j = blockIdx.x * 4 + w;
    int b0 = blockIdx.y * 8;
    int h = j >> 6;
    const float* wr = w_in + (size_t)2 * E * E + (size_t)j * E;
    float4 wv[4];
    #pragma unroll
    for (int r = 0; r < 4; r++) wv[r] = *(const float4*)(wr + r * 256 + l * 4);
    float acc[8];
    #pragma unroll
    for (int bb = 0; bb < 8; bb++) {
        const float* src = p + ((size_t)(b0 + bb) * H + h) * E;
        float a = 0.f;
        #pragma unroll
        for (int r = 0; r < 4; r++) a += dot4(wv[r], *(const float4*)(src + r * 256 + l * 4));
        acc[bb] = a;
    }
    bfly8(acc);
    if (l == 0) {
        float bias = b_in[2 * E + j];
        #pragma unroll
        for (int bb = 0; bb < 8; bb++) ctx[(size_t)(b0 + bb) * E + j] = acc[bb] + bias;
    }
}

// ---- 7. out = origin_q + strength * (ctx·Wout^T + bout), gated; lanes 0-7 store 8 batches ----
__global__ void k_out(const float* __restrict__ model, const float* __restrict__ w_out,
                      const float* __restrict__ b_out, const float* __restrict__ ctx,
                      const int* __restrict__ mp, const int* __restrict__ empty,
                      const float* __restrict__ strength_p, float* __restrict__ out) {
    int w = threadIdx.x >> 6, l = threadIdx.x & 63;
    int j = blockIdx.x * 4 + w;
    int b0 = blockIdx.y * 8;
    const float* wr = w_out + (size_t)j * E;
    float4 wv[4];
    #pragma unroll
    for (int r = 0; r < 4; r++) wv[r] = *(const float4*)(wr + r * 256 + l * 4);
    float acc[8];
    #pragma unroll
    for (int bb = 0; bb < 8; bb++) {
        const float* src = ctx + (size_t)(b0 + bb) * E;
        float a = 0.f;
        #pragma unroll
        for (int r = 0; r < 4; r++) a += dot4(wv[r], *(const float4*)(src + r * 256 + l * 4));
        acc[bb] = a;
    }
    bfly8(acc);
    if (l < 8) {
        float myacc = acc[0];
        #pragma unroll
        for (int bb = 1; bb < 8; bb++) myacc = (l == bb) ? acc[bb] : myacc;
        int b = b0 + l;
        int m = mp[b];
        float orig = model[((size_t)(b * S + m)) * E + j];
        float bias = b_out[j];
        float st = strength_p[0];
        out[(size_t)b * E + j] = empty[b] ? orig : orig + st * (myacc + bias);
    }
}

extern "C" void kernel_launch(void* const* d_in, const int* in_sizes, int n_in,
                              void* d_out, int out_size, void* d_ws, size_t ws_size,
                              hipStream_t stream) {
    const float* model     = (const float*)d_in[0];
    const float* knowledge = (const float*)d_in[1];
    const float* w_in      = (const float*)d_in[2];
    const float* b_in      = (const float*)d_in[3];
    const float* w_out     = (const float*)d_in[4];
    const float* b_out     = (const float*)d_in[5];
    const float* strength  = (const float*)d_in[6];
    const int*   ids       = (const int*)d_in[7];
    const int*   empty     = (const int*)d_in[8];
    const int*   know_id   = (const int*)d_in[9];
    const int*   mask_id   = (const int*)d_in[10];
    float* out = (float*)d_out;

    float* ws  = (float*)d_ws;
    int*   mp  = (int*)d_ws;
    float* q   = ws + W_Q;
    float* qk  = ws + W_QK;
    float* num = ws + W_NUM;
    float* qin = num;            // overlay: written by k_prep, consumed by k_q before k_attn writes num

    // partial-chunk count C from workspace budget (fixed per deployment -> graph-safe)
    int C = 8, nHalf = 1;
    {
        size_t need8 = ((size_t)W_NUM + 8u * 1048576u + 8u * 1024u + 1048576u + 65536u) * 4u;
        size_t need4 = ((size_t)W_NUM + 4u * 1048576u + 4u * 1024u + 1048576u + 65536u) * 4u;
        if (ws_size < need8) {
            if (ws_size < need4) { C = 2; nHalf = 4; }
            else                 { C = 4; nHalf = 2; }
        }
    }
    float* den = num + (size_t)C * 1048576u;
    float* p   = den + (size_t)C * 1024u;
    float* ctx = p + 1048576u;

    k_prep<<<BS, 256, 0, stream>>>(model, knowledge, ids, mask_id, know_id, mp, qin);
    k_q<<<dim3(256, 8), 256, 0, stream>>>(qin, w_in, b_in, q);
    k_qk<<<dim3(4, H, 8), 256, 0, stream>>>(w_in, q, qk);
    k_attn<<<dim3(C, BS), 512, 0, stream>>>(model, knowledge, ids, know_id, qk, num, den, nHalf);
    k_combine<<<dim3(1024), 256, 0, stream>>>(num, den, p, C);
    k_ctx<<<dim3(256, 8), 256, 0, stream>>>(w_in, b_in, p, ctx);
    k_out<<<dim3(256, 8), 256, 0, stream>>>(model, w_out, b_out, ctx, mp, empty, strength, out);
}

// Round 5
// 284.061 us; speedup vs baseline: 1.6041x; 1.2957x over previous
//
#include <hip/hip_runtime.h>

#define BS 64
#define S  512
#define E  1024
#define H  16
#define HD 64
#define SCALE 0.125f   // 1/sqrt(64)
#define CATT 8         // attention chunks (64 rows each)

// workspace float offsets
#define W_QIN  1024
#define W_QKBF 66560      // bf16 qk (SCALE-folded): 64*16*1024 ushorts = 524288 float slots
#define W_NUM  1115136    // 8 partial chunks x BS*H*E f32
#define W_DEN  9503744    // 8 x BS*H
#define W_CTX  9511936    // BS*E

typedef __attribute__((ext_vector_type(8))) short short8;
typedef __attribute__((ext_vector_type(4))) float floatx4;

__device__ __forceinline__ unsigned int pack_bf16(float a, float b) {
    unsigned int ua = __float_as_uint(a), ub = __float_as_uint(b);
    ua = (ua + 0x7fffu + ((ua >> 16) & 1u)) >> 16;
    ub = (ub + 0x7fffu + ((ub >> 16) & 1u)) >> 16;
    return ua | (ub << 16);
}

__device__ __forceinline__ void fma4(float4& acc, float s, const float4& v) {
    acc.x += s * v.x; acc.y += s * v.y; acc.z += s * v.z; acc.w += s * v.w;
}
__device__ __forceinline__ float dot4(const float4& a, const float4& b) {
    return a.x * b.x + a.y * b.y + a.z * b.z + a.w * b.w;
}
__device__ __forceinline__ void bfly8(float* a) {
    #pragma unroll
    for (int off = 32; off > 0; off >>= 1) {
        #pragma unroll
        for (int i = 0; i < 8; i++) a[i] += __shfl_xor(a[i], off, 64);
    }
}

// ---- 1. prep: mask position + gathered q-input row ----
__global__ void k_prep(const float* __restrict__ model, const float* __restrict__ knowledge,
                       const int* __restrict__ ids, const int* __restrict__ mask_id_p,
                       const int* __restrict__ kid_p, int* __restrict__ mp,
                       float* __restrict__ qin) {
    int b = blockIdx.x, tid = threadIdx.x;
    __shared__ int best;
    if (tid == 0) best = S;
    __syncthreads();
    int mid = mask_id_p[0];
    for (int s = tid; s < S; s += 256)
        if (ids[b * S + s] == mid) atomicMin(&best, s);
    __syncthreads();
    int m = (best == S) ? 0 : best;
    if (tid == 0) mp[b] = m;
    bool isk = (ids[b * S + m] == kid_p[0]);
    const float* qrow = isk ? knowledge + (size_t)b * E : model + ((size_t)(b * S + m)) * E;
    ((float4*)(qin + (size_t)b * E))[tid] = ((const float4*)qrow)[tid];
}

// ---- 2. fused q + qk -> qkbf (bf16, SCALE folded). block per (h, 4 batches) ----
__global__ void k_qgen(const float* __restrict__ qin, const float* __restrict__ w_in,
                       const float* __restrict__ b_in, unsigned short* __restrict__ qkbf) {
    int h = blockIdx.x, b0 = blockIdx.y * 4, t = threadIdx.x;
    __shared__ float qin_l[4][1024];
    __shared__ float qred[4][64][4];
    __shared__ float qs_l[4][64];
    // stage qin for 4 batches (coalesced)
    #pragma unroll
    for (int k = 0; k < 4; k++) {
        int idx4 = k * 256 + t;
        int bb = idx4 >> 8, col = (idx4 & 255) * 4;
        *(float4*)&qin_l[bb][col] = *(const float4*)(qin + (size_t)(b0 + bb) * E + col);
    }
    __syncthreads();
    // phase 1: q_h[d] partials (4 threads per d)
    {
        int d = t >> 2, part = t & 3;
        const float* wr = w_in + (size_t)(h * HD + d) * E + part * 256;
        float acc[4] = {0.f, 0.f, 0.f, 0.f};
        for (int i = 0; i < 64; i++) {
            float4 wv = *(const float4*)(wr + i * 4);
            #pragma unroll
            for (int bb = 0; bb < 4; bb++)
                acc[bb] += dot4(wv, *(const float4*)&qin_l[bb][part * 256 + i * 4]);
        }
        #pragma unroll
        for (int bb = 0; bb < 4; bb++) qred[bb][d][part] = acc[bb];
    }
    __syncthreads();
    if (t < 64) {
        float bias = b_in[h * HD + t];
        #pragma unroll
        for (int bb = 0; bb < 4; bb++)
            qs_l[bb][t] = qred[bb][t][0] + qred[bb][t][1] + qred[bb][t][2] + qred[bb][t][3] + bias;
    }
    __syncthreads();
    // phase 2: qk[e'] = SCALE * sum_d qs[d] * Wk[h*64+d][e']
    {
        int e0 = t * 4;
        const float* wk = w_in + (size_t)(E + h * HD) * E + e0;
        float4 acc[4];
        #pragma unroll
        for (int bb = 0; bb < 4; bb++) acc[bb] = make_float4(0.f, 0.f, 0.f, 0.f);
        for (int d = 0; d < HD; d++) {
            float4 wv = *(const float4*)(wk + (size_t)d * E);
            #pragma unroll
            for (int bb = 0; bb < 4; bb++) fma4(acc[bb], qs_l[bb][d], wv);
        }
        #pragma unroll
        for (int bb = 0; bb < 4; bb++) {
            uint2 pk;
            pk.x = pack_bf16(acc[bb].x * SCALE, acc[bb].y * SCALE);
            pk.y = pack_bf16(acc[bb].z * SCALE, acc[bb].w * SCALE);
            *(uint2*)&qkbf[((size_t)(b0 + bb) * H + h) * E + e0] = pk;
        }
    }
}

// ---- 3. fused attention via MFMA. block per (chunk c, batch b); 512 thr; 4 passes x 16 rows ----
__global__ __launch_bounds__(512, 4) void k_attn(
    const float* __restrict__ model, const float* __restrict__ knowledge,
    const int* __restrict__ ids, const int* __restrict__ kid_p,
    const unsigned short* __restrict__ qkbf, float* __restrict__ num, float* __restrict__ den) {
    __shared__ unsigned short Rbuf[16 * 1032];   // 16 rows x 1024 e (+8 pad) bf16
    __shared__ unsigned short Pbuf[16 * 40];     // [head][row 0..15 +pad] bf16
    __shared__ const float* rowp[64];
    int tid = threadIdx.x;
    int l = tid & 63, w = tid >> 6;
    int quad = l >> 4, lm = l & 15;
    int c = blockIdx.x, b = blockIdx.y;
    int s0 = c * 64;
    if (tid < 64) {
        int id = ids[b * S + s0 + tid];
        rowp[tid] = (id == kid_p[0]) ? knowledge + (size_t)b * E
                                     : model + ((size_t)(b * S + s0 + tid)) * E;
    }
    const unsigned short* qh = qkbf + ((size_t)b * H + lm) * E;  // head = lm (B-operand)
    floatx4 accn[8];
    #pragma unroll
    for (int i = 0; i < 8; i++) accn[i] = (floatx4)0.f;
    float accden = 0.f;
    int ebw = w * 8;   // this wave's 8 n-tiles (e = (ebw+i)*16 + lm)
    __syncthreads();

    for (int pass = 0; pass < 4; pass++) {
        // ---- stage 16 rows (64 KB fp32 -> 32 KB bf16), fully coalesced ----
        int rbase = pass * 16;
        #pragma unroll
        for (int k = 0; k < 8; k++) {
            int row = 2 * k + (tid >> 8);
            const float* rp = rowp[rbase + row];
            int col = (tid & 255) * 4;
            float4 v = *(const float4*)(rp + col);
            uint2 pk;
            pk.x = pack_bf16(v.x, v.y);
            pk.y = pack_bf16(v.z, v.w);
            *(uint2*)&Rbuf[row * 1032 + col] = pk;
        }
        __syncthreads();
        // ---- GEMM1 (wave 0): scores 16 rows x 16 heads, K=1024 ----
        if (w == 0) {
            floatx4 accs = (floatx4)0.f;
            for (int kk = 0; kk < 32; kk++) {
                short8 a = *(const short8*)(const void*)&Rbuf[lm * 1032 + kk * 32 + quad * 8];
                short8 bf = *(const short8*)(const void*)(qh + kk * 32 + quad * 8);
                accs = __builtin_amdgcn_mfma_f32_16x16x32_bf16(a, bf, accs, 0, 0, 0);
            }
            // C layout: head = lm, rows = quad*4 + reg. exp (SCALE pre-folded), den, P.
            float e0 = __expf(accs[0]), e1 = __expf(accs[1]);
            float e2 = __expf(accs[2]), e3 = __expf(accs[3]);
            float sum = e0 + e1 + e2 + e3;
            sum += __shfl_xor(sum, 16, 64);
            sum += __shfl_xor(sum, 32, 64);
            accden += sum;
            uint2 pw;
            pw.x = pack_bf16(e0, e1);
            pw.y = pack_bf16(e2, e3);
            *(uint2*)&Pbuf[lm * 40 + quad * 4] = pw;
        }
        __syncthreads();
        // ---- GEMM2 (all waves): num[h][e] += P^T(16h x 16rows,padded K=32) @ R(16rows x e) ----
        short8 afr = {};
        if (quad < 2) afr = *(const short8*)(const void*)&Pbuf[lm * 40 + quad * 8];
        #pragma unroll
        for (int i = 0; i < 8; i++) {
            int e = (ebw + i) * 16 + lm;
            short8 bfr = {};
            if (quad < 2) {
                #pragma unroll
                for (int j = 0; j < 8; j++)
                    bfr[j] = (short)Rbuf[(quad * 8 + j) * 1032 + e];
            }
            accn[i] = __builtin_amdgcn_mfma_f32_16x16x32_bf16(afr, bfr, accn[i], 0, 0, 0);
        }
        __syncthreads();
    }
    // write num: lane holds heads quad*4+reg at e=(ebw+i)*16+lm
    size_t base = ((size_t)(c * BS + b) * H) * E;
    #pragma unroll
    for (int i = 0; i < 8; i++) {
        int e = (ebw + i) * 16 + lm;
        num[base + (size_t)(quad * 4 + 0) * E + e] = accn[i][0];
        num[base + (size_t)(quad * 4 + 1) * E + e] = accn[i][1];
        num[base + (size_t)(quad * 4 + 2) * E + e] = accn[i][2];
        num[base + (size_t)(quad * 4 + 3) * E + e] = accn[i][3];
    }
    if (w == 0 && l < 16) den[(size_t)(c * BS + b) * H + l] = accden;
}

// ---- 4. combine + ctx: block per (h, 4 batches) ----
__global__ void k_pc(const float* __restrict__ num, const float* __restrict__ den,
                     const float* __restrict__ w_in, const float* __restrict__ b_in,
                     float* __restrict__ ctx) {
    int h = blockIdx.x, b0 = blockIdx.y * 4, t = threadIdx.x;
    __shared__ float p_l[4][1024];
    __shared__ float cred[4][64][4];
    __shared__ float inv_l[4];
    // combine partials (raw sums; den division deferred)
    #pragma unroll
    for (int k = 0; k < 4; k++) {
        int idx4 = k * 256 + t;
        int bb = idx4 >> 8, e4 = (idx4 & 255) * 4;
        float4 a = make_float4(0.f, 0.f, 0.f, 0.f);
        for (int cc = 0; cc < CATT; cc++) {
            float4 v = *(const float4*)(num + (((size_t)(cc * BS + b0 + bb) * H + h) * E) + e4);
            a.x += v.x; a.y += v.y; a.z += v.z; a.w += v.w;
        }
        *(float4*)&p_l[bb][e4] = a;
    }
    if (t < 4) {
        float ds = 0.f;
        for (int cc = 0; cc < CATT; cc++) ds += den[(size_t)(cc * BS + b0 + t) * H + h];
        inv_l[t] = 1.0f / ds;
    }
    __syncthreads();
    // ctx[j = h*64 + jj] = inv * sum_e p[e] * Wv[j][e] + bv[j]
    {
        int jj = t >> 2, part = t & 3;
        const float* wr = w_in + (size_t)(2 * E + h * HD + jj) * E + part * 256;
        float acc[4] = {0.f, 0.f, 0.f, 0.f};
        for (int i = 0; i < 64; i++) {
            float4 wv = *(const float4*)(wr + i * 4);
            #pragma unroll
            for (int bb = 0; bb < 4; bb++)
                acc[bb] += dot4(wv, *(const float4*)&p_l[bb][part * 256 + i * 4]);
        }
        #pragma unroll
        for (int bb = 0; bb < 4; bb++) cred[bb][jj][part] = acc[bb];
    }
    __syncthreads();
    if (t < 64) {
        float bias = b_in[2 * E + h * HD + t];
        #pragma unroll
        for (int bb = 0; bb < 4; bb++) {
            float s = cred[bb][t][0] + cred[bb][t][1] + cred[bb][t][2] + cred[bb][t][3];
            ctx[(size_t)(b0 + bb) * E + h * HD + t] = inv_l[bb] * s + bias;
        }
    }
}

// ---- 5. out = origin_q + strength * (ctx @ Wout^T + bout), gated ----
__global__ void k_out(const float* __restrict__ model, const float* __restrict__ w_out,
                      const float* __restrict__ b_out, const float* __restrict__ ctx,
                      const int* __restrict__ mp, const int* __restrict__ empty,
                      const float* __restrict__ strength_p, float* __restrict__ out) {
    int w = threadIdx.x >> 6, l = threadIdx.x & 63;
    int j = blockIdx.x * 4 + w;
    int b0 = blockIdx.y * 8;
    const float* wr = w_out + (size_t)j * E;
    float4 wv[4];
    #pragma unroll
    for (int r = 0; r < 4; r++) wv[r] = *(const float4*)(wr + r * 256 + l * 4);
    float acc[8];
    #pragma unroll
    for (int bb = 0; bb < 8; bb++) {
        const float* src = ctx + (size_t)(b0 + bb) * E;
        float a = 0.f;
        #pragma unroll
        for (int r = 0; r < 4; r++) a += dot4(wv[r], *(const float4*)(src + r * 256 + l * 4));
        acc[bb] = a;
    }
    bfly8(acc);
    if (l < 8) {
        float myacc = acc[0];
        #pragma unroll
        for (int bb = 1; bb < 8; bb++) myacc = (l == bb) ? acc[bb] : myacc;
        int b = b0 + l;
        int m = mp[b];
        float orig = model[((size_t)(b * S + m)) * E + j];
        float bias = b_out[j];
        float st = strength_p[0];
        out[(size_t)b * E + j] = empty[b] ? orig : orig + st * (myacc + bias);
    }
}

extern "C" void kernel_launch(void* const* d_in, const int* in_sizes, int n_in,
                              void* d_out, int out_size, void* d_ws, size_t ws_size,
                              hipStream_t stream) {
    const float* model     = (const float*)d_in[0];
    const float* knowledge = (const float*)d_in[1];
    const float* w_in      = (const float*)d_in[2];
    const float* b_in      = (const float*)d_in[3];
    const float* w_out     = (const float*)d_in[4];
    const float* b_out     = (const float*)d_in[5];
    const float* strength  = (const float*)d_in[6];
    const int*   ids       = (const int*)d_in[7];
    const int*   empty     = (const int*)d_in[8];
    const int*   know_id   = (const int*)d_in[9];
    const int*   mask_id   = (const int*)d_in[10];
    float* out = (float*)d_out;

    float* ws  = (float*)d_ws;
    int*   mp  = (int*)d_ws;
    float* qin = ws + W_QIN;
    unsigned short* qkbf = (unsigned short*)(ws + W_QKBF);
    float* num = ws + W_NUM;
    float* den = ws + W_DEN;
    float* ctx = ws + W_CTX;

    k_prep<<<BS, 256, 0, stream>>>(model, knowledge, ids, mask_id, know_id, mp, qin);
    k_qgen<<<dim3(H, 16), 256, 0, stream>>>(qin, w_in, b_in, qkbf);
    k_attn<<<dim3(CATT, BS), 512, 0, stream>>>(model, knowledge, ids, know_id, qkbf, num, den);
    k_pc<<<dim3(H, 16), 256, 0, stream>>>(num, den, w_in, b_in, ctx);
    k_out<<<dim3(256, 8), 256, 0, stream>>>(model, w_out, b_out, ctx, mp, empty, strength, out);
}

// Round 6
// 280.944 us; speedup vs baseline: 1.6218x; 1.0111x over previous
//
#include <hip/hip_runtime.h>

#define BS 64
#define S  512
#define E  1024
#define H  16
#define HD 64
#define SCALE 0.125f   // 1/sqrt(64)
#define CATT 8         // attention chunks (64 rows each)

// workspace float offsets
#define W_QIN  1024
#define W_QKBF 66560      // bf16 qk (SCALE-folded): 64*16*1024 ushorts = 524288 float slots
#define W_NUM  1115136    // 8 partial chunks x BS*H*E f32
#define W_DEN  9503744    // 8 x BS*H
#define W_CTX  9511936    // BS*E

typedef __attribute__((ext_vector_type(8))) short short8;
typedef __attribute__((ext_vector_type(4))) float floatx4;

union S8u { uint2 u2[2]; short8 s; };

__device__ __forceinline__ unsigned short bf16c(float x) {
    unsigned int u = __float_as_uint(x);
    return (unsigned short)((u + 0x7fffu + ((u >> 16) & 1u)) >> 16);
}
__device__ __forceinline__ unsigned int pack_bf16(float a, float b) {
    return (unsigned int)bf16c(a) | ((unsigned int)bf16c(b) << 16);
}
__device__ __forceinline__ void fma4(float4& acc, float s, const float4& v) {
    acc.x += s * v.x; acc.y += s * v.y; acc.z += s * v.z; acc.w += s * v.w;
}
__device__ __forceinline__ float dot4(const float4& a, const float4& b) {
    return a.x * b.x + a.y * b.y + a.z * b.z + a.w * b.w;
}
__device__ __forceinline__ void bfly8(float* a) {
    #pragma unroll
    for (int off = 32; off > 0; off >>= 1) {
        #pragma unroll
        for (int i = 0; i < 8; i++) a[i] += __shfl_xor(a[i], off, 64);
    }
}

// ---- 1. prep: mask position + gathered q-input row ----
__global__ void k_prep(const float* __restrict__ model, const float* __restrict__ knowledge,
                       const int* __restrict__ ids, const int* __restrict__ mask_id_p,
                       const int* __restrict__ kid_p, int* __restrict__ mp,
                       float* __restrict__ qin) {
    int b = blockIdx.x, tid = threadIdx.x;
    __shared__ int best;
    if (tid == 0) best = S;
    __syncthreads();
    int mid = mask_id_p[0];
    for (int s = tid; s < S; s += 256)
        if (ids[b * S + s] == mid) atomicMin(&best, s);
    __syncthreads();
    int m = (best == S) ? 0 : best;
    if (tid == 0) mp[b] = m;
    bool isk = (ids[b * S + m] == kid_p[0]);
    const float* qrow = isk ? knowledge + (size_t)b * E : model + ((size_t)(b * S + m)) * E;
    ((float4*)(qin + (size_t)b * E))[tid] = ((const float4*)qrow)[tid];
}

// ---- 2. fused q + qk -> qkbf (bf16, SCALE folded). block per (h, 4 batches) ----
__global__ void k_qgen(const float* __restrict__ qin, const float* __restrict__ w_in,
                       const float* __restrict__ b_in, unsigned short* __restrict__ qkbf) {
    int h = blockIdx.x, b0 = blockIdx.y * 4, t = threadIdx.x;
    __shared__ float qin_l[4][1024];
    __shared__ float qred[4][64][4];
    __shared__ float qs_l[4][64];
    #pragma unroll
    for (int k = 0; k < 4; k++) {
        int idx4 = k * 256 + t;
        int bb = idx4 >> 8, col = (idx4 & 255) * 4;
        *(float4*)&qin_l[bb][col] = *(const float4*)(qin + (size_t)(b0 + bb) * E + col);
    }
    __syncthreads();
    {
        int d = t >> 2, part = t & 3;
        const float* wr = w_in + (size_t)(h * HD + d) * E + part * 256;
        float acc[4] = {0.f, 0.f, 0.f, 0.f};
        for (int i = 0; i < 64; i++) {
            float4 wv = *(const float4*)(wr + i * 4);
            #pragma unroll
            for (int bb = 0; bb < 4; bb++)
                acc[bb] += dot4(wv, *(const float4*)&qin_l[bb][part * 256 + i * 4]);
        }
        #pragma unroll
        for (int bb = 0; bb < 4; bb++) qred[bb][d][part] = acc[bb];
    }
    __syncthreads();
    if (t < 64) {
        float bias = b_in[h * HD + t];
        #pragma unroll
        for (int bb = 0; bb < 4; bb++)
            qs_l[bb][t] = qred[bb][t][0] + qred[bb][t][1] + qred[bb][t][2] + qred[bb][t][3] + bias;
    }
    __syncthreads();
    {
        int e0 = t * 4;
        const float* wk = w_in + (size_t)(E + h * HD) * E + e0;
        float4 acc[4];
        #pragma unroll
        for (int bb = 0; bb < 4; bb++) acc[bb] = make_float4(0.f, 0.f, 0.f, 0.f);
        for (int d = 0; d < HD; d++) {
            float4 wv = *(const float4*)(wk + (size_t)d * E);
            #pragma unroll
            for (int bb = 0; bb < 4; bb++) fma4(acc[bb], qs_l[bb][d], wv);
        }
        #pragma unroll
        for (int bb = 0; bb < 4; bb++) {
            uint2 pk;
            pk.x = pack_bf16(acc[bb].x * SCALE, acc[bb].y * SCALE);
            pk.y = pack_bf16(acc[bb].z * SCALE, acc[bb].w * SCALE);
            *(uint2*)&qkbf[((size_t)(b0 + bb) * H + h) * E + e0] = pk;
        }
    }
}

// ---- 3. fused attention via MFMA, dual-layout staging ----
// block per (chunk c, batch b); 512 thr (8 waves); 4 passes x 16 rows.
// Rbuf  row-major  (GEMM1 A: scores), stride 1032 shorts (16B-aligned b128)
// RbufT col-major  (GEMM2 B: num),   stride 20 shorts (16 rows + pad, 8B-aligned b64)
__global__ __launch_bounds__(512, 4) void k_attn(
    const float* __restrict__ model, const float* __restrict__ knowledge,
    const int* __restrict__ ids, const int* __restrict__ kid_p,
    const unsigned short* __restrict__ qkbf, float* __restrict__ num, float* __restrict__ den) {
    __shared__ __align__(16) unsigned char Ubuf[73984];   // Rbuf(33024) + RbufT(40960) | Tbuf(65792)
    unsigned short* Rbuf  = (unsigned short*)Ubuf;
    unsigned short* RbufT = (unsigned short*)(Ubuf + 33024);
    float* Tbuf = (float*)Ubuf;
    __shared__ unsigned short Pbuf[16 * 40];              // P[h][row], rows 0-15 valid
    __shared__ float Sred[4][16][17];                     // GEMM1 partials per wave
    __shared__ unsigned long long kmask_s;

    int tid = threadIdx.x;
    int w = tid >> 6, l = tid & 63;
    int quad = l >> 4, lm = l & 15;
    int c = blockIdx.x, b = blockIdx.y;
    int s0 = c * 64;

    if (w == 0) {
        int id = ids[b * S + s0 + l];
        unsigned long long mk = __ballot(id == kid_p[0]);
        if (l == 0) kmask_s = mk;
    }
    floatx4 accn[8];
    #pragma unroll
    for (int i = 0; i < 8; i++) accn[i] = (floatx4)0.f;
    float accden = 0.f;
    const float* kb = knowledge + (size_t)b * E;
    const float* mb = model + (size_t)b * S * E;
    const unsigned short* qh = qkbf + ((size_t)b * H + lm) * E;
    __syncthreads();
    unsigned long long kmask = kmask_s;

    for (int pass = 0; pass < 4; pass++) {
        int rb = pass * 16;
        // ---- stage 16 rows into Rbuf (row-major) AND RbufT (transposed), coalesced 4B loads ----
        #pragma unroll
        for (int g = 0; g < 4; g++) {
            int r0 = g * 4;
            const float* rp0 = ((kmask >> (rb + r0 + 0)) & 1ull) ? kb : mb + (size_t)(s0 + rb + r0 + 0) * E;
            const float* rp1 = ((kmask >> (rb + r0 + 1)) & 1ull) ? kb : mb + (size_t)(s0 + rb + r0 + 1) * E;
            const float* rp2 = ((kmask >> (rb + r0 + 2)) & 1ull) ? kb : mb + (size_t)(s0 + rb + r0 + 2) * E;
            const float* rp3 = ((kmask >> (rb + r0 + 3)) & 1ull) ? kb : mb + (size_t)(s0 + rb + r0 + 3) * E;
            #pragma unroll
            for (int cc = 0; cc < 2; cc++) {
                int col = cc * 512 + tid;
                unsigned short h0 = bf16c(rp0[col]);
                unsigned short h1 = bf16c(rp1[col]);
                unsigned short h2 = bf16c(rp2[col]);
                unsigned short h3 = bf16c(rp3[col]);
                Rbuf[(r0 + 0) * 1032 + col] = h0;
                Rbuf[(r0 + 1) * 1032 + col] = h1;
                Rbuf[(r0 + 2) * 1032 + col] = h2;
                Rbuf[(r0 + 3) * 1032 + col] = h3;
                uint2 pk;
                pk.x = (unsigned int)h0 | ((unsigned int)h1 << 16);
                pk.y = (unsigned int)h2 | ((unsigned int)h3 << 16);
                *(uint2*)&RbufT[col * 20 + r0] = pk;
            }
        }
        __syncthreads();
        // ---- GEMM1 (waves 0-3, K=256 slice each): scores 16 rows x 16 heads ----
        if (w < 4) {
            floatx4 acs = (floatx4)0.f;
            #pragma unroll
            for (int t = 0; t < 8; t++) {
                int kk = w * 8 + t;
                short8 a  = *(const short8*)(const void*)&Rbuf[lm * 1032 + kk * 32 + quad * 8];
                short8 bf = *(const short8*)(const void*)(qh + kk * 32 + quad * 8);
                acs = __builtin_amdgcn_mfma_f32_16x16x32_bf16(a, bf, acs, 0, 0, 0);
            }
            Sred[w][quad * 4 + 0][lm] = acs[0];
            Sred[w][quad * 4 + 1][lm] = acs[1];
            Sred[w][quad * 4 + 2][lm] = acs[2];
            Sred[w][quad * 4 + 3][lm] = acs[3];
        }
        __syncthreads();
        // ---- combine + exp + P (wave 0) ----
        if (w == 0) {
            float ex[4];
            #pragma unroll
            for (int r = 0; r < 4; r++) {
                int row = quad * 4 + r;
                float s = Sred[0][row][lm] + Sred[1][row][lm] + Sred[2][row][lm] + Sred[3][row][lm];
                ex[r] = __expf(s);          // SCALE folded into qkbf
                accden += ex[r];
            }
            uint2 pw;
            pw.x = (unsigned int)bf16c(ex[0]) | ((unsigned int)bf16c(ex[1]) << 16);
            pw.y = (unsigned int)bf16c(ex[2]) | ((unsigned int)bf16c(ex[3]) << 16);
            *(uint2*)&Pbuf[lm * 40 + quad * 4] = pw;
        }
        __syncthreads();
        // ---- GEMM2 (all waves): num[h][e] += P(16h x 16r, K padded 32) @ R(16r x e) ----
        short8 afr = {};
        if (quad < 2) afr = *(const short8*)(const void*)&Pbuf[lm * 40 + quad * 8];
        #pragma unroll
        for (int i = 0; i < 8; i++) {
            int e = (w * 8 + i) * 16 + lm;
            S8u bb; bb.s = (short8){};
            if (quad < 2) {
                bb.u2[0] = *(const uint2*)&RbufT[e * 20 + quad * 8];
                bb.u2[1] = *(const uint2*)&RbufT[e * 20 + quad * 8 + 4];
            }
            accn[i] = __builtin_amdgcn_mfma_f32_16x16x32_bf16(afr, bb.s, accn[i], 0, 0, 0);
        }
        __syncthreads();
    }
    // ---- epilogue: transpose accn through LDS, store num coalesced ----
    #pragma unroll
    for (int i = 0; i < 8; i++) {
        int e = (w * 8 + i) * 16 + lm;
        Tbuf[(quad * 4 + 0) * 1028 + e] = accn[i][0];
        Tbuf[(quad * 4 + 1) * 1028 + e] = accn[i][1];
        Tbuf[(quad * 4 + 2) * 1028 + e] = accn[i][2];
        Tbuf[(quad * 4 + 3) * 1028 + e] = accn[i][3];
    }
    if (w == 0) {
        accden += __shfl_xor(accden, 16, 64);
        accden += __shfl_xor(accden, 32, 64);
        if (l < 16) den[(size_t)(c * BS + b) * H + l] = accden;
    }
    __syncthreads();
    size_t base = ((size_t)(c * BS + b) * H) * E;
    #pragma unroll
    for (int k = 0; k < 8; k++) {
        int idx4 = k * 512 + tid;
        int h = idx4 >> 8, e4 = (idx4 & 255) * 4;
        *(float4*)(num + base + (size_t)idx4 * 4) = *(const float4*)&Tbuf[h * 1028 + e4];
    }
}

// ---- 4. combine + ctx: block per (h, 4 batches) ----
__global__ void k_pc(const float* __restrict__ num, const float* __restrict__ den,
                     const float* __restrict__ w_in, const float* __restrict__ b_in,
                     float* __restrict__ ctx) {
    int h = blockIdx.x, b0 = blockIdx.y * 4, t = threadIdx.x;
    __shared__ float p_l[4][1024];
    __shared__ float cred[4][64][4];
    __shared__ float inv_l[4];
    #pragma unroll
    for (int k = 0; k < 4; k++) {
        int idx4 = k * 256 + t;
        int bb = idx4 >> 8, e4 = (idx4 & 255) * 4;
        float4 a = make_float4(0.f, 0.f, 0.f, 0.f);
        for (int cc = 0; cc < CATT; cc++) {
            float4 v = *(const float4*)(num + (((size_t)(cc * BS + b0 + bb) * H + h) * E) + e4);
            a.x += v.x; a.y += v.y; a.z += v.z; a.w += v.w;
        }
        *(float4*)&p_l[bb][e4] = a;
    }
    if (t < 4) {
        float ds = 0.f;
        for (int cc = 0; cc < CATT; cc++) ds += den[(size_t)(cc * BS + b0 + t) * H + h];
        inv_l[t] = 1.0f / ds;
    }
    __syncthreads();
    {
        int jj = t >> 2, part = t & 3;
        const float* wr = w_in + (size_t)(2 * E + h * HD + jj) * E + part * 256;
        float acc[4] = {0.f, 0.f, 0.f, 0.f};
        for (int i = 0; i < 64; i++) {
            float4 wv = *(const float4*)(wr + i * 4);
            #pragma unroll
            for (int bb = 0; bb < 4; bb++)
                acc[bb] += dot4(wv, *(const float4*)&p_l[bb][part * 256 + i * 4]);
        }
        #pragma unroll
        for (int bb = 0; bb < 4; bb++) cred[bb][jj][part] = acc[bb];
    }
    __syncthreads();
    if (t < 64) {
        float bias = b_in[2 * E + h * HD + t];
        #pragma unroll
        for (int bb = 0; bb < 4; bb++) {
            float s = cred[bb][t][0] + cred[bb][t][1] + cred[bb][t][2] + cred[bb][t][3];
            ctx[(size_t)(b0 + bb) * E + h * HD + t] = inv_l[bb] * s + bias;
        }
    }
}

// ---- 5. out = origin_q + strength * (ctx @ Wout^T + bout), gated ----
__global__ void k_out(const float* __restrict__ model, const float* __restrict__ w_out,
                      const float* __restrict__ b_out, const float* __restrict__ ctx,
                      const int* __restrict__ mp, const int* __restrict__ empty,
                      const float* __restrict__ strength_p, float* __restrict__ out) {
    int w = threadIdx.x >> 6, l = threadIdx.x & 63;
    int j = blockIdx.x * 4 + w;
    int b0 = blockIdx.y * 8;
    const float* wr = w_out + (size_t)j * E;
    float4 wv[4];
    #pragma unroll
    for (int r = 0; r < 4; r++) wv[r] = *(const float4*)(wr + r * 256 + l * 4);
    float acc[8];
    #pragma unroll
    for (int bb = 0; bb < 8; bb++) {
        const float* src = ctx + (size_t)(b0 + bb) * E;
        float a = 0.f;
        #pragma unroll
        for (int r = 0; r < 4; r++) a += dot4(wv[r], *(const float4*)(src + r * 256 + l * 4));
        acc[bb] = a;
    }
    bfly8(acc);
    if (l < 8) {
        float myacc = acc[0];
        #pragma unroll
        for (int bb = 1; bb < 8; bb++) myacc = (l == bb) ? acc[bb] : myacc;
        int b = b0 + l;
        int m = mp[b];
        float orig = model[((size_t)(b * S + m)) * E + j];
        float bias = b_out[j];
        float st = strength_p[0];
        out[(size_t)b * E + j] = empty[b] ? orig : orig + st * (myacc + bias);
    }
}

extern "C" void kernel_launch(void* const* d_in, const int* in_sizes, int n_in,
                              void* d_out, int out_size, void* d_ws, size_t ws_size,
                              hipStream_t stream) {
    const float* model     = (const float*)d_in[0];
    const float* knowledge = (const float*)d_in[1];
    const float* w_in      = (const float*)d_in[2];
    const float* b_in      = (const float*)d_in[3];
    const float* w_out     = (const float*)d_in[4];
    const float* b_out     = (const float*)d_in[5];
    const float* strength  = (const float*)d_in[6];
    const int*   ids       = (const int*)d_in[7];
    const int*   empty     = (const int*)d_in[8];
    const int*   know_id   = (const int*)d_in[9];
    const int*   mask_id   = (const int*)d_in[10];
    float* out = (float*)d_out;

    float* ws  = (float*)d_ws;
    int*   mp  = (int*)d_ws;
    float* qin = ws + W_QIN;
    unsigned short* qkbf = (unsigned short*)(ws + W_QKBF);
    float* num = ws + W_NUM;
    float* den = ws + W_DEN;
    float* ctx = ws + W_CTX;

    k_prep<<<BS, 256, 0, stream>>>(model, knowledge, ids, mask_id, know_id, mp, qin);
    k_qgen<<<dim3(H, 16), 256, 0, stream>>>(qin, w_in, b_in, qkbf);
    k_attn<<<dim3(CATT, BS), 512, 0, stream>>>(model, knowledge, ids, know_id, qkbf, num, den);
    k_pc<<<dim3(H, 16), 256, 0, stream>>>(num, den, w_in, b_in, ctx);
    k_out<<<dim3(256, 8), 256, 0, stream>>>(model, w_out, b_out, ctx, mp, empty, strength, out);
}